// Round 15
// baseline (311.554 us; speedup 1.0000x reference)
//
#include <hip/hip_runtime.h>
#include <hip/hip_fp16.h>

#define N_NODES 50000
#define N_EDGES 1600000
#define D_IN    128
#define D_HID   50
#define D_OUT   10
#define K_CHEB  5

// bucket sort params: bucket = row >> 8 (196 buckets of 256 rows), block-private strips
#define P1_BLOCKS 256
#define EPB       (N_EDGES / P1_BLOCKS)   // 6250 edges per pass-1 block
#define NBUCK2    256                     // padded bucket count (196 used)
#define NB_USED2  196
#define BCAP2     96                      // strip capacity; mean 32, sd ~5.7 -> +11 sd

#define WH_ELEMS  (K_CHEB * 64 * D_IN)    // 40960 halfs (W^T, n padded to 64)
#define WH_BLOCKS ((WH_ELEMS + 255) / 256)  // 160

#define VROW      64                      // padded hidden row (halfs) = 128 B
#define VSTRIDE   ((size_t)(N_NODES + 1) * VROW)   // +1 zeroed pad row

typedef _Float16 half8_t __attribute__((ext_vector_type(8)));
typedef float    f32x4_t __attribute__((ext_vector_type(4)));

// Clenshaw in hidden space: v_k = dinv .* (x @ W_k)  (fused MFMA GEMM), then
//   b3 = v3 + 2M v4;  b2 = v2 + 2M b3 - v4;  b1 = v1 + 2M b2 - b3;
//   S  = v0 +  M b1 - b2;   out = log_softmax(relu(sdeg*S + bias) @ fc_w + fc_b)
// with (M v)[r] = -dinv2[r] * sum_{c in N(r)} v[c]. SpMM rows are 128 B (64 halfs).
// Zero-degree nodes: dinv=0 -> v rows 0 -> bias path (accepted, P ~ 6e-10).
// R15: (1) vgemm splits work 5x — one wave per (16-node group, term): R12-R14 all
// plateaued ~45-50 us at 3128 waves (3/SIMD device-wide = nothing hides latency;
// LDS-vs-scatter-vs-pipeline all neutral). group=w/5 keeps a group's 5 terms in one
// block for L1 x reuse. (2) CSR buckets 49->196 (row>>8): pass2 ran on 49/256 CUs.

// ------- fused prep: pass1 bucket scatter + Wh build + pad-row clears ----
__global__ __launch_bounds__(256) void pass1_kernel(const int* __restrict__ row,
                                                    const int* __restrict__ col,
                                                    unsigned int* __restrict__ store,
                                                    int* __restrict__ bcnt,
                                                    const float* __restrict__ W,
                                                    __half* __restrict__ Wh,
                                                    __half* __restrict__ v,
                                                    __half* __restrict__ b1) {
    int tid = threadIdx.x;
    int blk = blockIdx.x;
    if (blk >= P1_BLOCKS) {
        int wb = blk - P1_BLOCKS;
        if (wb < WH_BLOCKS) {            // Wh = fp16 W^T padded: Wh[t][n<64][i<128]
            int idx = wb * 256 + tid;
            if (idx < WH_ELEMS) {
                int i = idx & 127;
                int n = (idx >> 7) & 63;
                int t = idx >> 13;
                float vv = (n < D_HID) ? W[t * D_IN * D_HID + i * D_HID + n] : 0.f;
                Wh[idx] = __float2half(vv);
            }
        } else {                         // zero pad rows: v4 (64h), b1 (64h)
            if (tid < VROW) {
                v[4 * VSTRIDE + (size_t)N_NODES * VROW + tid] = __float2half(0.f);
                b1[(size_t)N_NODES * VROW + tid] = __float2half(0.f);
            }
        }
        return;
    }
    __shared__ int cnt[NBUCK2];
    cnt[tid] = 0;
    __syncthreads();
    int base = blk * EPB;
    size_t sb = (size_t)blk * (NBUCK2 * BCAP2);
    for (int i = tid; i < EPB; i += 256) {
        int r = row[base + i];
        int c = col[base + i];
        int b = r >> 8;
        int pos = atomicAdd(&cnt[b], 1);
        if (pos >= BCAP2) pos = BCAP2 - 1;   // memory-safety clamp; P(hit) ~ 0
        store[sb + b * BCAP2 + pos] = ((unsigned int)(r & 255) << 16) | (unsigned int)c;
    }
    __syncthreads();
    bcnt[blk * NBUCK2 + tid] = cnt[tid];
}

// ---------------- pass 2: per-bucket CSR build (one block per bucket, 196 blocks) ----
__global__ __launch_bounds__(512) void pass2_kernel(const unsigned int* __restrict__ store,
                                                    const int* __restrict__ bcnt,
                                                    int* __restrict__ row_start,
                                                    float* __restrict__ dinv,
                                                    float* __restrict__ dinv2,
                                                    float* __restrict__ sdeg,
                                                    int* __restrict__ ewc) {
    __shared__ int hist[256];
    __shared__ int off[256];
    __shared__ int fill[256];
    __shared__ int sb_part[512];
    __shared__ int pscan[256];
    __shared__ int s_bbase;
    int tid = threadIdx.x;
    int b = blockIdx.x;

    // phase 0: bucket totals + exclusive prefix (redundant per block)
    {
        int bt = tid & 255, seg = tid >> 8;       // 2 segs x 128 strips
        int sum = 0;
        for (int s = seg * 128; s < seg * 128 + 128; ++s) sum += bcnt[s * NBUCK2 + bt];
        sb_part[tid] = sum;
    }
    __syncthreads();
    if (tid < 256) pscan[tid] = sb_part[tid] + sb_part[256 + tid];
    __syncthreads();
    for (int o = 1; o < 256; o <<= 1) {
        int vv = (tid < 256 && tid >= o) ? pscan[tid - o] : 0;
        __syncthreads();
        if (tid < 256) pscan[tid] += vv;
        __syncthreads();
    }
    if (tid == 0) {
        s_bbase = (b == 0) ? 0 : pscan[b - 1];
        if (b == 0) row_start[N_NODES] = pscan[255];
    }
    if (tid < 256) hist[tid] = 0;
    __syncthreads();
    int bbase_b = s_bbase;

    int strip = tid >> 1;        // 0..255
    int sub   = tid & 1;
    int sn = bcnt[strip * NBUCK2 + b];
    size_t sb = (size_t)strip * (NBUCK2 * BCAP2) + b * BCAP2;
    // phase A: degree histogram — 2 threads sweep each strip
    for (int i = sub; i < sn; i += 2)
        atomicAdd(&hist[store[sb + i] >> 16], 1);
    __syncthreads();
    int d = (tid < 256) ? hist[tid] : 0;
    if (tid < 256) off[tid] = d;
    __syncthreads();
    for (int o = 1; o < 256; o <<= 1) {
        int vv = (tid < 256 && tid >= o) ? off[tid - o] : 0;
        __syncthreads();
        if (tid < 256) off[tid] += vv;
        __syncthreads();
    }
    if (tid < 256) {
        int excl = off[tid] - d + bbase_b;
        hist[tid] = excl;        // reuse as per-row global base
        fill[tid] = 0;
        int r = (b << 8) + tid;
        if (r < N_NODES) {
            row_start[r] = excl;
            float fd = (float)d;
            dinv[r]  = d ? rsqrtf(fd)  : 0.f;
            dinv2[r] = d ? (1.f / fd)  : 0.f;
            sdeg[r]  = d ? sqrtf(fd)   : 0.f;
        }
    }
    __syncthreads();
    // phase C: scatter cols into final CSR (writes confined to this bucket's region)
    for (int i = sub; i < sn; i += 2) {
        unsigned int vv = store[sb + i];
        int rl = vv >> 16;
        int c = vv & 0xffff;
        int p = atomicAdd(&fill[rl], 1);
        ewc[hist[rl] + p] = c;
    }
}

// ---------------- V = dinv .* (x @ [W0..W4]) — one wave per (group, term) ------------
// 15625 waves (5x R14). group = w/5 -> a group's 5 terms land in the same block,
// sharing its 16 x-rows through L1. 16 independent A-frag loads + 16 MFMA + 4 stores
// per wave; no barriers, no LDS. D[m=j][n=node]: lane holds node=lane&15,
// j = jt*16 + quad*4 + reg -> direct 8 B stores (dinv folded in).
__global__ __launch_bounds__(256) void vgemm_kernel(const float* __restrict__ x,
                                                    const float* __restrict__ dinv,
                                                    const __half* __restrict__ Wh,
                                                    __half* __restrict__ v) {
    int tid = threadIdx.x;
    int lane = tid & 63;
    int wv = __builtin_amdgcn_readfirstlane(tid >> 6);
    int w = blockIdx.x * 4 + wv;
    int grp = w / 5;
    int t = w - grp * 5;
    int m = lane & 15;          // node within group (B n-index)
    int quad = lane >> 4;       // k-quad

    int node = grp * 16 + m;
    bool ok = (node < N_NODES);
    int ln = ok ? node : (N_NODES - 1);   // clamped load row (masked at store)
    float dv = ok ? dinv[node] : 0.f;

    // B-frags: x row, 4 k-chunks of 8 floats -> half8
    half8_t bfr[4];
    #pragma unroll
    for (int ks = 0; ks < 4; ++ks) {
        const float4* xr = (const float4*)(x + (size_t)ln * D_IN + ks * 32 + quad * 8);
        float4 fA = xr[0], fB = xr[1];
        half8_t h;
        h[0] = (_Float16)fA.x; h[1] = (_Float16)fA.y;
        h[2] = (_Float16)fA.z; h[3] = (_Float16)fA.w;
        h[4] = (_Float16)fB.x; h[5] = (_Float16)fB.y;
        h[6] = (_Float16)fB.z; h[7] = (_Float16)fB.w;
        bfr[ks] = h;
    }

    // A-frags for this term: 16 independent loads (Wh is L2-hot, 80 KB)
    const __half* Wt = Wh + t * (64 * D_IN);
    half8_t afr[4][4];
    #pragma unroll
    for (int ks = 0; ks < 4; ++ks) {
        int ko = ks * 32 + quad * 8;
        #pragma unroll
        for (int jt = 0; jt < 4; ++jt)
            afr[ks][jt] = *(const half8_t*)(Wt + (jt * 16 + m) * D_IN + ko);
    }

    f32x4_t acc[4];
    #pragma unroll
    for (int jt = 0; jt < 4; ++jt) acc[jt] = (f32x4_t)0.f;
    #pragma unroll
    for (int ks = 0; ks < 4; ++ks)
        #pragma unroll
        for (int jt = 0; jt < 4; ++jt)
            acc[jt] = __builtin_amdgcn_mfma_f32_16x16x32_f16(afr[ks][jt], bfr[ks], acc[jt], 0, 0, 0);

    if (ok) {
        __half* dst = v + t * VSTRIDE + (size_t)node * VROW + quad * 4;
        #pragma unroll
        for (int jt = 0; jt < 4; ++jt) {
            __half2 h0 = __float22half2_rn(make_float2(acc[jt][0] * dv, acc[jt][1] * dv));
            __half2 h1 = __float22half2_rn(make_float2(acc[jt][2] * dv, acc[jt][3] * dv));
            uint2 u;
            u.x = *(unsigned int*)&h0;
            u.y = *(unsigned int*)&h1;
            *(uint2*)(dst + jt * 16) = u;    // 8 B at col jt*16+quad*4
        }
    }
}

// ---------------- Clenshaw SpMM step in hidden space ----------------
// dst[r] = addv[r] + (-alphaM*dinv2[r]) * sum_{c in N(r)} src[c]  - do_sub*subv[r]
// 1 wave/row; 8 lanes x 16 B cover the 128 B row (full 64 B quad coalescing);
// 8 edges per gather inst (lane>>3 selects via 3-level cndmask from s_loaded cc[8]);
// 4 insts = 32 edges per iteration. ewc over-allocated by +32 ints (masked).
__global__ __launch_bounds__(512) void prop_kernel(const int* __restrict__ row_start,
                                                   const int* __restrict__ ewc,
                                                   const float* __restrict__ dinv2,
                                                   const __half* __restrict__ src,
                                                   const __half* __restrict__ addv,
                                                   const __half* __restrict__ subv,
                                                   float alphaM, int do_sub,
                                                   __half* __restrict__ dst) {
    int tid = threadIdx.x;
    int lane = tid & 63;
    int wv = __builtin_amdgcn_readfirstlane(tid >> 6);  // 0..7
    int r = blockIdx.x * 8 + wv;                        // 6250*8 == 50000
    int e0 = row_start[r], e1 = row_start[r + 1];
    float fac = -alphaM * dinv2[r];
    int l = lane & 7;            // uint4 unit within row (8 x 16 B = 128 B)
    int g = lane >> 3;           // edge slot 0..7
    const uint4* src16 = (const uint4*)src;   // row stride 8 uint4
    float ac[8];
    #pragma unroll
    for (int j = 0; j < 8; ++j) ac[j] = 0.f;
    for (int e = e0; e < e1; e += 32) {
        #pragma unroll
        for (int i = 0; i < 4; ++i) {
            int base = e + 8 * i;
            int c0 = ewc[base + 0];          // uniform -> s_load (dwordx8)
            int c1 = ewc[base + 1];
            int c2 = ewc[base + 2];
            int c3 = ewc[base + 3];
            int c4 = ewc[base + 4];
            int c5 = ewc[base + 5];
            int c6 = ewc[base + 6];
            int c7 = ewc[base + 7];
            int cA = (g & 1) ? c1 : c0;
            int cB = (g & 1) ? c3 : c2;
            int cC = (g & 1) ? c5 : c4;
            int cD = (g & 1) ? c7 : c6;
            int cE = (g & 2) ? cB : cA;
            int cF = (g & 2) ? cD : cC;
            int cl = (g & 4) ? cF : cE;
            if (base + g >= e1) cl = N_NODES;    // zeroed pad row
            uint4 u = src16[(size_t)cl * 8 + l];
            float2 f0 = __half22float2(*(__half2*)&u.x);
            float2 f1 = __half22float2(*(__half2*)&u.y);
            float2 f2 = __half22float2(*(__half2*)&u.z);
            float2 f3 = __half22float2(*(__half2*)&u.w);
            ac[0] += f0.x; ac[1] += f0.y; ac[2] += f1.x; ac[3] += f1.y;
            ac[4] += f2.x; ac[5] += f2.y; ac[6] += f3.x; ac[7] += f3.y;
        }
    }
    // reduce across the 8 edge slots (lane bits 3,4,5)
    #pragma unroll
    for (int k = 8; k <= 32; k <<= 1) {
        #pragma unroll
        for (int j = 0; j < 8; ++j) ac[j] += __shfl_xor(ac[j], k);
    }
    if (g == 0) {
        size_t o = (size_t)r * 8 + l;    // uint4 index
        uint4 av = ((const uint4*)addv)[o];
        float2 av0 = __half22float2(*(__half2*)&av.x);
        float2 av1 = __half22float2(*(__half2*)&av.y);
        float2 av2 = __half22float2(*(__half2*)&av.z);
        float2 av3 = __half22float2(*(__half2*)&av.w);
        float r0 = av0.x + fac * ac[0];
        float r1 = av0.y + fac * ac[1];
        float r2 = av1.x + fac * ac[2];
        float r3 = av1.y + fac * ac[3];
        float r4 = av2.x + fac * ac[4];
        float r5 = av2.y + fac * ac[5];
        float r6 = av3.x + fac * ac[6];
        float r7 = av3.y + fac * ac[7];
        if (do_sub) {
            uint4 sv = ((const uint4*)subv)[o];
            float2 sv0 = __half22float2(*(__half2*)&sv.x);
            float2 sv1 = __half22float2(*(__half2*)&sv.y);
            float2 sv2 = __half22float2(*(__half2*)&sv.z);
            float2 sv3 = __half22float2(*(__half2*)&sv.w);
            r0 -= sv0.x; r1 -= sv0.y; r2 -= sv1.x; r3 -= sv1.y;
            r4 -= sv2.x; r5 -= sv2.y; r6 -= sv3.x; r7 -= sv3.y;
        }
        __half2 h0 = __float22half2_rn(make_float2(r0, r1));
        __half2 h1 = __float22half2_rn(make_float2(r2, r3));
        __half2 h2 = __float22half2_rn(make_float2(r4, r5));
        __half2 h3 = __float22half2_rn(make_float2(r6, r7));
        uint4 u;
        u.x = *(unsigned int*)&h0;
        u.y = *(unsigned int*)&h1;
        u.z = *(unsigned int*)&h2;
        u.w = *(unsigned int*)&h3;
        ((uint4*)dst)[o] = u;
    }
}

// ---------------- epilogue: relu(sdeg*S + bias) -> FC -> log_softmax ----------------
__global__ __launch_bounds__(256) void final_kernel(const __half* __restrict__ S,
                                                    const float* __restrict__ sdeg,
                                                    const float* __restrict__ cheb_b,
                                                    const float* __restrict__ fc_w,
                                                    const float* __restrict__ fc_b,
                                                    float* __restrict__ out) {
    int r = blockIdx.x * blockDim.x + threadIdx.x;
    if (r >= N_NODES) return;
    float sc = sdeg[r];
    const __half2* s2 = (const __half2*)(S + (size_t)r * VROW);
    float h[D_HID];
    #pragma unroll
    for (int i = 0; i < D_HID / 2; ++i) {
        float2 f = __half22float2(s2[i]);
        float v0 = sc * f.x + cheb_b[2 * i];
        float v1 = sc * f.y + cheb_b[2 * i + 1];
        h[2 * i]     = v0 > 0.f ? v0 : 0.f;
        h[2 * i + 1] = v1 > 0.f ? v1 : 0.f;
    }
    float lg[D_OUT];
    #pragma unroll
    for (int o = 0; o < D_OUT; ++o) lg[o] = fc_b[o];
    #pragma unroll 2
    for (int i = 0; i < D_HID; ++i) {
        float hv = h[i];
        #pragma unroll
        for (int o = 0; o < D_OUT; ++o) lg[o] += hv * fc_w[i * D_OUT + o];
    }
    float mx = lg[0];
    #pragma unroll
    for (int o = 1; o < D_OUT; ++o) mx = fmaxf(mx, lg[o]);
    float s = 0.f;
    #pragma unroll
    for (int o = 0; o < D_OUT; ++o) s += __expf(lg[o] - mx);
    float ls = __logf(s);
    size_t oo = (size_t)r * D_OUT;
    #pragma unroll
    for (int o = 0; o < D_OUT; ++o) out[oo + o] = lg[o] - mx - ls;
}

extern "C" void kernel_launch(void* const* d_in, const int* in_sizes, int n_in,
                              void* d_out, int out_size, void* d_ws, size_t ws_size,
                              hipStream_t stream) {
    const float* x      = (const float*)d_in[0];
    const int*   edge   = (const int*)d_in[1];
    const float* cheb_w = (const float*)d_in[2];
    const float* cheb_b = (const float*)d_in[3];
    const float* fc_w   = (const float*)d_in[4];
    const float* fc_b   = (const float*)d_in[5];
    float* out = (float*)d_out;

    const int* erow = edge;
    const int* ecol = edge + N_EDGES;

    uintptr_t p = ((uintptr_t)d_ws + 255) & ~(uintptr_t)255;
    auto alloc = [&](size_t bytes) {
        uintptr_t q = p;
        p = (p + bytes + 255) & ~(uintptr_t)255;
        return (void*)q;
    };
    unsigned int* store = (unsigned int*)alloc((size_t)P1_BLOCKS * NBUCK2 * BCAP2 * 4);  // 25.2 MB
    int*    bcnt      = (int*)alloc((size_t)P1_BLOCKS * NBUCK2 * 4);
    int*    row_start = (int*)alloc((size_t)(N_NODES + 1) * 4);
    float*  dinv      = (float*)alloc((size_t)N_NODES * 4);
    float*  dinv2     = (float*)alloc((size_t)N_NODES * 4);
    float*  sdeg      = (float*)alloc((size_t)N_NODES * 4);
    int*    ewc       = (int*)alloc((size_t)(N_EDGES + 32) * 4);   // +32 pad
    __half* Wh        = (__half*)alloc((size_t)WH_ELEMS * 2);      // 80 KB
    __half* Sbuf      = (__half*)alloc(VSTRIDE * 2);               // 6.4 MB (S result)
    __half* v         = (__half*)alloc(5 * VSTRIDE * 2);           // v0..v4, 32 MB
    __half* b1        = (__half*)alloc(VSTRIDE * 2);               // 6.4 MB

    // buffer reuse: store (dead after pass2) hosts b3,b2
    __half* b3 = (__half*)store;
    __half* b2 = (__half*)store + VSTRIDE;
    __half* S  = Sbuf;

    // fused prep: bucket scatter + Wh + pad clears (v4, b1)
    pass1_kernel<<<P1_BLOCKS + WH_BLOCKS + 1, 256, 0, stream>>>(
        erow, ecol, store, bcnt, cheb_w, Wh, v, b1);
    pass2_kernel<<<NB_USED2, 512, 0, stream>>>(store, bcnt, row_start,
                                               dinv, dinv2, sdeg, ewc);
    // store now dead -> zero b3/b2 pad rows (gather targets)
    hipMemsetAsync(b3 + (size_t)N_NODES * VROW, 0, VROW * 2, stream);
    hipMemsetAsync(b2 + (size_t)N_NODES * VROW, 0, VROW * 2, stream);

    // v_t = dinv .* (x @ W_t) — one wave per (16-node group, term)
    const int NWAVE = ((N_NODES + 15) / 16) * K_CHEB;   // 15625
    const int GBK = (NWAVE + 3) / 4;                    // 3907 blocks
    vgemm_kernel<<<GBK, 256, 0, stream>>>(x, dinv, Wh, v);

    // Clenshaw: 4 SpMMs on 64-half rows
    __half* v0 = v;
    __half* v1 = v + 1 * VSTRIDE;
    __half* v2 = v + 2 * VSTRIDE;
    __half* v3 = v + 3 * VSTRIDE;
    __half* v4 = v + 4 * VSTRIDE;
    const int PB = N_NODES / 8;   // 6250 blocks x 8 waves
    // b3 = v3 + 2M v4
    prop_kernel<<<PB, 512, 0, stream>>>(row_start, ewc, dinv2, v4, v3, v3, 2.f, 0, b3);
    // b2 = v2 + 2M b3 - v4
    prop_kernel<<<PB, 512, 0, stream>>>(row_start, ewc, dinv2, b3, v2, v4, 2.f, 1, b2);
    // b1 = v1 + 2M b2 - b3
    prop_kernel<<<PB, 512, 0, stream>>>(row_start, ewc, dinv2, b2, v1, b3, 2.f, 1, b1);
    // S = v0 + M b1 - b2
    prop_kernel<<<PB, 512, 0, stream>>>(row_start, ewc, dinv2, b1, v0, b2, 1.f, 1, S);

    // out = log_softmax(relu(sdeg*S + bias) @ fc_w + fc_b)
    final_kernel<<<(N_NODES + 255) / 256, 256, 0, stream>>>(S, sdeg, cheb_b,
                                                            fc_w, fc_b, out);
}

// Round 16
// 291.909 us; speedup vs baseline: 1.0673x; 1.0673x over previous
//
#include <hip/hip_runtime.h>
#include <hip/hip_fp16.h>

#define N_NODES 50000
#define N_EDGES 1600000
#define D_IN    128
#define D_HID   50
#define D_OUT   10
#define K_CHEB  5

// bucket sort params: bucket = row >> 8 (196 buckets of 256 rows), block-private strips
#define P1_BLOCKS 256
#define EPB       (N_EDGES / P1_BLOCKS)   // 6250 edges per pass-1 block
#define NBUCK2    256                     // padded bucket count (196 used)
#define NB_USED2  196
#define BCAP2     96                      // strip capacity; mean 32, sd ~5.7 -> +11 sd

#define WH_ELEMS  (K_CHEB * 64 * D_IN)    // 40960 halfs (W^T, n padded to 64)
#define WH_BLOCKS ((WH_ELEMS + 255) / 256)  // 160

#define VROW      64                      // padded hidden row (halfs) = 128 B
#define VSTRIDE   ((size_t)(N_NODES + 1) * VROW)   // +1 zeroed pad row

#define NGROUP    (N_NODES / 16)          // 3125 node groups (exact)
#define VG_SPAN   512                     // waves per term
#define VG_WAVES  (K_CHEB * VG_SPAN)      // 2560 waves -> 640 blocks x 4 waves

typedef _Float16 half8_t __attribute__((ext_vector_type(8)));
typedef float    f32x4_t __attribute__((ext_vector_type(4)));

// Clenshaw in hidden space: v_k = dinv .* (x @ W_k)  (fused MFMA GEMM), then
//   b3 = v3 + 2M v4;  b2 = v2 + 2M b3 - v4;  b1 = v1 + 2M b2 - b3;
//   S  = v0 +  M b1 - b2;   out = log_softmax(relu(sdeg*S + bias) @ fc_w + fc_b)
// with (M v)[r] = -dinv2[r] * sum_{c in N(r)} v[c]. SpMM rows are 128 B (64 halfs).
// Zero-degree nodes: dinv=0 -> v rows 0 -> bias path (accepted, P ~ 6e-10).
// R16: (1) persistent-weight vgemm — R12-R15 all plateaued 45-58 us because every
// variant re-loaded the 16 Wh A-frags per node-group (request-bound). Now each wave
// holds one term's A-frags in registers (loaded once) and grid-strides node groups:
// 9 requests/group instead of 28. (2) prop edge indices via one per-lane dword load
// instead of 8 s_loads + cndmask tree.

// ------- fused prep: pass1 bucket scatter + Wh build + pad-row clears ----
__global__ __launch_bounds__(256) void pass1_kernel(const int* __restrict__ row,
                                                    const int* __restrict__ col,
                                                    unsigned int* __restrict__ store,
                                                    int* __restrict__ bcnt,
                                                    const float* __restrict__ W,
                                                    __half* __restrict__ Wh,
                                                    __half* __restrict__ v,
                                                    __half* __restrict__ b1) {
    int tid = threadIdx.x;
    int blk = blockIdx.x;
    if (blk >= P1_BLOCKS) {
        int wb = blk - P1_BLOCKS;
        if (wb < WH_BLOCKS) {            // Wh = fp16 W^T padded: Wh[t][n<64][i<128]
            int idx = wb * 256 + tid;
            if (idx < WH_ELEMS) {
                int i = idx & 127;
                int n = (idx >> 7) & 63;
                int t = idx >> 13;
                float vv = (n < D_HID) ? W[t * D_IN * D_HID + i * D_HID + n] : 0.f;
                Wh[idx] = __float2half(vv);
            }
        } else {                         // zero pad rows: v4 (64h), b1 (64h)
            if (tid < VROW) {
                v[4 * VSTRIDE + (size_t)N_NODES * VROW + tid] = __float2half(0.f);
                b1[(size_t)N_NODES * VROW + tid] = __float2half(0.f);
            }
        }
        return;
    }
    __shared__ int cnt[NBUCK2];
    cnt[tid] = 0;
    __syncthreads();
    int base = blk * EPB;
    size_t sb = (size_t)blk * (NBUCK2 * BCAP2);
    for (int i = tid; i < EPB; i += 256) {
        int r = row[base + i];
        int c = col[base + i];
        int b = r >> 8;
        int pos = atomicAdd(&cnt[b], 1);
        if (pos >= BCAP2) pos = BCAP2 - 1;   // memory-safety clamp; P(hit) ~ 0
        store[sb + b * BCAP2 + pos] = ((unsigned int)(r & 255) << 16) | (unsigned int)c;
    }
    __syncthreads();
    bcnt[blk * NBUCK2 + tid] = cnt[tid];
}

// ---------------- pass 2: per-bucket CSR build (one block per bucket, 196 blocks) ----
__global__ __launch_bounds__(512) void pass2_kernel(const unsigned int* __restrict__ store,
                                                    const int* __restrict__ bcnt,
                                                    int* __restrict__ row_start,
                                                    float* __restrict__ dinv,
                                                    float* __restrict__ dinv2,
                                                    float* __restrict__ sdeg,
                                                    int* __restrict__ ewc) {
    __shared__ int hist[256];
    __shared__ int off[256];
    __shared__ int fill[256];
    __shared__ int sb_part[512];
    __shared__ int pscan[256];
    __shared__ int s_bbase;
    int tid = threadIdx.x;
    int b = blockIdx.x;

    // phase 0: bucket totals + exclusive prefix (redundant per block)
    {
        int bt = tid & 255, seg = tid >> 8;       // 2 segs x 128 strips
        int sum = 0;
        for (int s = seg * 128; s < seg * 128 + 128; ++s) sum += bcnt[s * NBUCK2 + bt];
        sb_part[tid] = sum;
    }
    __syncthreads();
    if (tid < 256) pscan[tid] = sb_part[tid] + sb_part[256 + tid];
    __syncthreads();
    for (int o = 1; o < 256; o <<= 1) {
        int vv = (tid < 256 && tid >= o) ? pscan[tid - o] : 0;
        __syncthreads();
        if (tid < 256) pscan[tid] += vv;
        __syncthreads();
    }
    if (tid == 0) {
        s_bbase = (b == 0) ? 0 : pscan[b - 1];
        if (b == 0) row_start[N_NODES] = pscan[255];
    }
    if (tid < 256) hist[tid] = 0;
    __syncthreads();
    int bbase_b = s_bbase;

    int strip = tid >> 1;        // 0..255
    int sub   = tid & 1;
    int sn = bcnt[strip * NBUCK2 + b];
    size_t sb = (size_t)strip * (NBUCK2 * BCAP2) + b * BCAP2;
    // phase A: degree histogram — 2 threads sweep each strip
    for (int i = sub; i < sn; i += 2)
        atomicAdd(&hist[store[sb + i] >> 16], 1);
    __syncthreads();
    int d = (tid < 256) ? hist[tid] : 0;
    if (tid < 256) off[tid] = d;
    __syncthreads();
    for (int o = 1; o < 256; o <<= 1) {
        int vv = (tid < 256 && tid >= o) ? off[tid - o] : 0;
        __syncthreads();
        if (tid < 256) off[tid] += vv;
        __syncthreads();
    }
    if (tid < 256) {
        int excl = off[tid] - d + bbase_b;
        hist[tid] = excl;        // reuse as per-row global base
        fill[tid] = 0;
        int r = (b << 8) + tid;
        if (r < N_NODES) {
            row_start[r] = excl;
            float fd = (float)d;
            dinv[r]  = d ? rsqrtf(fd)  : 0.f;
            dinv2[r] = d ? (1.f / fd)  : 0.f;
            sdeg[r]  = d ? sqrtf(fd)   : 0.f;
        }
    }
    __syncthreads();
    // phase C: scatter cols into final CSR (writes confined to this bucket's region)
    for (int i = sub; i < sn; i += 2) {
        unsigned int vv = store[sb + i];
        int rl = vv >> 16;
        int c = vv & 0xffff;
        int p = atomicAdd(&fill[rl], 1);
        ewc[hist[rl] + p] = c;
    }
}

// ---------------- V = dinv .* (x @ [W0..W4]) — persistent-weight MFMA ----------------
// 2560 waves; wave w holds term t=w/512's 16 A-frags in registers (loaded once) and
// grid-strides node groups g = idx, idx+512, ... (3125 groups; 50000 = 3125*16 so no
// row masking). Per group: 8 x-loads (prefetched into regs during MFMA of previous
// group) + 16 MFMA + 4 stores. D[m=j][n=node]: lane holds node=lane&15,
// j = jt*16 + quad*4 + reg -> direct 8 B stores (dinv folded in). No LDS/barriers.
__global__ __launch_bounds__(256) void vgemm_kernel(const float* __restrict__ x,
                                                    const float* __restrict__ dinv,
                                                    const __half* __restrict__ Wh,
                                                    __half* __restrict__ v) {
    int tid = threadIdx.x;
    int lane = tid & 63;
    int wv = __builtin_amdgcn_readfirstlane(tid >> 6);
    int w = blockIdx.x * 4 + wv;          // 0..2559; 512%4==0 -> t uniform per block
    int t = w / VG_SPAN;                  // 0..4
    int idx = w - t * VG_SPAN;            // 0..511
    int m = lane & 15;                    // node within group (B n-index)
    int quad = lane >> 4;                 // k-quad

    // persistent A-frags for term t (64 VGPRs, loaded once per wave; Wh is L2-hot)
    const __half* Wt = Wh + t * (64 * D_IN);
    half8_t afr[4][4];
    #pragma unroll
    for (int ks = 0; ks < 4; ++ks) {
        int ko = ks * 32 + quad * 8;
        #pragma unroll
        for (int jt = 0; jt < 4; ++jt)
            afr[ks][jt] = *(const half8_t*)(Wt + (jt * 16 + m) * D_IN + ko);
    }

    __half* vt = v + t * VSTRIDE;

    // prologue: fetch first group's x row slice (8 float4 = 32 VGPRs)
    float4 pf[8];
    int g = idx;
    {
        const float* xr = x + (size_t)(g * 16 + m) * D_IN;
        #pragma unroll
        for (int ks = 0; ks < 4; ++ks) {
            pf[2 * ks]     = *(const float4*)(xr + ks * 32 + quad * 8);
            pf[2 * ks + 1] = *(const float4*)(xr + ks * 32 + quad * 8 + 4);
        }
    }

    for (; g < NGROUP; g += VG_SPAN) {
        int node = g * 16 + m;
        float dv = dinv[node];
        // convert prefetched x to fp16 B-frags
        half8_t bfr[4];
        #pragma unroll
        for (int ks = 0; ks < 4; ++ks) {
            float4 fA = pf[2 * ks], fB = pf[2 * ks + 1];
            half8_t h;
            h[0] = (_Float16)fA.x; h[1] = (_Float16)fA.y;
            h[2] = (_Float16)fA.z; h[3] = (_Float16)fA.w;
            h[4] = (_Float16)fB.x; h[5] = (_Float16)fB.y;
            h[6] = (_Float16)fB.z; h[7] = (_Float16)fB.w;
            bfr[ks] = h;
        }
        // prefetch next group's x while MFMAs run
        int gn = g + VG_SPAN;
        if (gn < NGROUP) {
            const float* xr = x + (size_t)(gn * 16 + m) * D_IN;
            #pragma unroll
            for (int ks = 0; ks < 4; ++ks) {
                pf[2 * ks]     = *(const float4*)(xr + ks * 32 + quad * 8);
                pf[2 * ks + 1] = *(const float4*)(xr + ks * 32 + quad * 8 + 4);
            }
        }
        f32x4_t acc[4];
        #pragma unroll
        for (int jt = 0; jt < 4; ++jt) acc[jt] = (f32x4_t)0.f;
        #pragma unroll
        for (int ks = 0; ks < 4; ++ks)
            #pragma unroll
            for (int jt = 0; jt < 4; ++jt)
                acc[jt] = __builtin_amdgcn_mfma_f32_16x16x32_f16(afr[ks][jt], bfr[ks], acc[jt], 0, 0, 0);
        __half* dst = vt + (size_t)node * VROW + quad * 4;
        #pragma unroll
        for (int jt = 0; jt < 4; ++jt) {
            __half2 h0 = __float22half2_rn(make_float2(acc[jt][0] * dv, acc[jt][1] * dv));
            __half2 h1 = __float22half2_rn(make_float2(acc[jt][2] * dv, acc[jt][3] * dv));
            uint2 u;
            u.x = *(unsigned int*)&h0;
            u.y = *(unsigned int*)&h1;
            *(uint2*)(dst + jt * 16) = u;    // 8 B at col jt*16+quad*4
        }
    }
}

// ---------------- Clenshaw SpMM step in hidden space ----------------
// dst[r] = addv[r] + (-alphaM*dinv2[r]) * sum_{c in N(r)} src[c]  - do_sub*subv[r]
// 1 wave/row; 8 lanes x 16 B cover the 128 B row (full 64 B quad coalescing);
// 8 edges per gather inst; edge index via one per-lane dword load (8 distinct
// dwords = 1 line, broadcast within slot groups). ewc over-allocated +32 (masked).
__global__ __launch_bounds__(512) void prop_kernel(const int* __restrict__ row_start,
                                                   const int* __restrict__ ewc,
                                                   const float* __restrict__ dinv2,
                                                   const __half* __restrict__ src,
                                                   const __half* __restrict__ addv,
                                                   const __half* __restrict__ subv,
                                                   float alphaM, int do_sub,
                                                   __half* __restrict__ dst) {
    int tid = threadIdx.x;
    int lane = tid & 63;
    int wv = __builtin_amdgcn_readfirstlane(tid >> 6);  // 0..7
    int r = blockIdx.x * 8 + wv;                        // 6250*8 == 50000
    int e0 = row_start[r], e1 = row_start[r + 1];
    float fac = -alphaM * dinv2[r];
    int l = lane & 7;            // uint4 unit within row (8 x 16 B = 128 B)
    int g = lane >> 3;           // edge slot 0..7
    const uint4* src16 = (const uint4*)src;   // row stride 8 uint4
    float ac[8];
    #pragma unroll
    for (int j = 0; j < 8; ++j) ac[j] = 0.f;
    for (int e = e0; e < e1; e += 32) {
        #pragma unroll
        for (int i = 0; i < 4; ++i) {
            int base = e + 8 * i;
            int cl = ewc[base + g];              // per-lane load, 1 line / instr
            if (base + g >= e1) cl = N_NODES;    // zeroed pad row
            uint4 u = src16[(size_t)cl * 8 + l];
            float2 f0 = __half22float2(*(__half2*)&u.x);
            float2 f1 = __half22float2(*(__half2*)&u.y);
            float2 f2 = __half22float2(*(__half2*)&u.z);
            float2 f3 = __half22float2(*(__half2*)&u.w);
            ac[0] += f0.x; ac[1] += f0.y; ac[2] += f1.x; ac[3] += f1.y;
            ac[4] += f2.x; ac[5] += f2.y; ac[6] += f3.x; ac[7] += f3.y;
        }
    }
    // reduce across the 8 edge slots (lane bits 3,4,5)
    #pragma unroll
    for (int k = 8; k <= 32; k <<= 1) {
        #pragma unroll
        for (int j = 0; j < 8; ++j) ac[j] += __shfl_xor(ac[j], k);
    }
    if (g == 0) {
        size_t o = (size_t)r * 8 + l;    // uint4 index
        uint4 av = ((const uint4*)addv)[o];
        float2 av0 = __half22float2(*(__half2*)&av.x);
        float2 av1 = __half22float2(*(__half2*)&av.y);
        float2 av2 = __half22float2(*(__half2*)&av.z);
        float2 av3 = __half22float2(*(__half2*)&av.w);
        float r0 = av0.x + fac * ac[0];
        float r1 = av0.y + fac * ac[1];
        float r2 = av1.x + fac * ac[2];
        float r3 = av1.y + fac * ac[3];
        float r4 = av2.x + fac * ac[4];
        float r5 = av2.y + fac * ac[5];
        float r6 = av3.x + fac * ac[6];
        float r7 = av3.y + fac * ac[7];
        if (do_sub) {
            uint4 sv = ((const uint4*)subv)[o];
            float2 sv0 = __half22float2(*(__half2*)&sv.x);
            float2 sv1 = __half22float2(*(__half2*)&sv.y);
            float2 sv2 = __half22float2(*(__half2*)&sv.z);
            float2 sv3 = __half22float2(*(__half2*)&sv.w);
            r0 -= sv0.x; r1 -= sv0.y; r2 -= sv1.x; r3 -= sv1.y;
            r4 -= sv2.x; r5 -= sv2.y; r6 -= sv3.x; r7 -= sv3.y;
        }
        __half2 h0 = __float22half2_rn(make_float2(r0, r1));
        __half2 h1 = __float22half2_rn(make_float2(r2, r3));
        __half2 h2 = __float22half2_rn(make_float2(r4, r5));
        __half2 h3 = __float22half2_rn(make_float2(r6, r7));
        uint4 u;
        u.x = *(unsigned int*)&h0;
        u.y = *(unsigned int*)&h1;
        u.z = *(unsigned int*)&h2;
        u.w = *(unsigned int*)&h3;
        ((uint4*)dst)[o] = u;
    }
}

// ---------------- epilogue: relu(sdeg*S + bias) -> FC -> log_softmax ----------------
__global__ __launch_bounds__(256) void final_kernel(const __half* __restrict__ S,
                                                    const float* __restrict__ sdeg,
                                                    const float* __restrict__ cheb_b,
                                                    const float* __restrict__ fc_w,
                                                    const float* __restrict__ fc_b,
                                                    float* __restrict__ out) {
    int r = blockIdx.x * blockDim.x + threadIdx.x;
    if (r >= N_NODES) return;
    float sc = sdeg[r];
    const __half2* s2 = (const __half2*)(S + (size_t)r * VROW);
    float h[D_HID];
    #pragma unroll
    for (int i = 0; i < D_HID / 2; ++i) {
        float2 f = __half22float2(s2[i]);
        float v0 = sc * f.x + cheb_b[2 * i];
        float v1 = sc * f.y + cheb_b[2 * i + 1];
        h[2 * i]     = v0 > 0.f ? v0 : 0.f;
        h[2 * i + 1] = v1 > 0.f ? v1 : 0.f;
    }
    float lg[D_OUT];
    #pragma unroll
    for (int o = 0; o < D_OUT; ++o) lg[o] = fc_b[o];
    #pragma unroll 2
    for (int i = 0; i < D_HID; ++i) {
        float hv = h[i];
        #pragma unroll
        for (int o = 0; o < D_OUT; ++o) lg[o] += hv * fc_w[i * D_OUT + o];
    }
    float mx = lg[0];
    #pragma unroll
    for (int o = 1; o < D_OUT; ++o) mx = fmaxf(mx, lg[o]);
    float s = 0.f;
    #pragma unroll
    for (int o = 0; o < D_OUT; ++o) s += __expf(lg[o] - mx);
    float ls = __logf(s);
    size_t oo = (size_t)r * D_OUT;
    #pragma unroll
    for (int o = 0; o < D_OUT; ++o) out[oo + o] = lg[o] - mx - ls;
}

extern "C" void kernel_launch(void* const* d_in, const int* in_sizes, int n_in,
                              void* d_out, int out_size, void* d_ws, size_t ws_size,
                              hipStream_t stream) {
    const float* x      = (const float*)d_in[0];
    const int*   edge   = (const int*)d_in[1];
    const float* cheb_w = (const float*)d_in[2];
    const float* cheb_b = (const float*)d_in[3];
    const float* fc_w   = (const float*)d_in[4];
    const float* fc_b   = (const float*)d_in[5];
    float* out = (float*)d_out;

    const int* erow = edge;
    const int* ecol = edge + N_EDGES;

    uintptr_t p = ((uintptr_t)d_ws + 255) & ~(uintptr_t)255;
    auto alloc = [&](size_t bytes) {
        uintptr_t q = p;
        p = (p + bytes + 255) & ~(uintptr_t)255;
        return (void*)q;
    };
    unsigned int* store = (unsigned int*)alloc((size_t)P1_BLOCKS * NBUCK2 * BCAP2 * 4);  // 25.2 MB
    int*    bcnt      = (int*)alloc((size_t)P1_BLOCKS * NBUCK2 * 4);
    int*    row_start = (int*)alloc((size_t)(N_NODES + 1) * 4);
    float*  dinv      = (float*)alloc((size_t)N_NODES * 4);
    float*  dinv2     = (float*)alloc((size_t)N_NODES * 4);
    float*  sdeg      = (float*)alloc((size_t)N_NODES * 4);
    int*    ewc       = (int*)alloc((size_t)(N_EDGES + 32) * 4);   // +32 pad
    __half* Wh        = (__half*)alloc((size_t)WH_ELEMS * 2);      // 80 KB
    __half* Sbuf      = (__half*)alloc(VSTRIDE * 2);               // 6.4 MB (S result)
    __half* v         = (__half*)alloc(5 * VSTRIDE * 2);           // v0..v4, 32 MB
    __half* b1        = (__half*)alloc(VSTRIDE * 2);               // 6.4 MB

    // buffer reuse: store (dead after pass2) hosts b3,b2
    __half* b3 = (__half*)store;
    __half* b2 = (__half*)store + VSTRIDE;
    __half* S  = Sbuf;

    // fused prep: bucket scatter + Wh + pad clears (v4, b1)
    pass1_kernel<<<P1_BLOCKS + WH_BLOCKS + 1, 256, 0, stream>>>(
        erow, ecol, store, bcnt, cheb_w, Wh, v, b1);
    pass2_kernel<<<NB_USED2, 512, 0, stream>>>(store, bcnt, row_start,
                                               dinv, dinv2, sdeg, ewc);
    // store now dead -> zero b3/b2 pad rows (gather targets)
    hipMemsetAsync(b3 + (size_t)N_NODES * VROW, 0, VROW * 2, stream);
    hipMemsetAsync(b2 + (size_t)N_NODES * VROW, 0, VROW * 2, stream);

    // v_t = dinv .* (x @ W_t) — persistent-weight MFMA, 2560 waves
    vgemm_kernel<<<VG_WAVES / 4, 256, 0, stream>>>(x, dinv, Wh, v);

    // Clenshaw: 4 SpMMs on 64-half rows
    __half* v0 = v;
    __half* v1 = v + 1 * VSTRIDE;
    __half* v2 = v + 2 * VSTRIDE;
    __half* v3 = v + 3 * VSTRIDE;
    __half* v4 = v + 4 * VSTRIDE;
    const int PB = N_NODES / 8;   // 6250 blocks x 8 waves
    // b3 = v3 + 2M v4
    prop_kernel<<<PB, 512, 0, stream>>>(row_start, ewc, dinv2, v4, v3, v3, 2.f, 0, b3);
    // b2 = v2 + 2M b3 - v4
    prop_kernel<<<PB, 512, 0, stream>>>(row_start, ewc, dinv2, b3, v2, v4, 2.f, 1, b2);
    // b1 = v1 + 2M b2 - b3
    prop_kernel<<<PB, 512, 0, stream>>>(row_start, ewc, dinv2, b2, v1, b3, 2.f, 1, b1);
    // S = v0 + M b1 - b2
    prop_kernel<<<PB, 512, 0, stream>>>(row_start, ewc, dinv2, b1, v0, b2, 1.f, 1, S);

    // out = log_softmax(relu(sdeg*S + bias) @ fc_w + fc_b)
    final_kernel<<<(N_NODES + 255) / 256, 256, 0, stream>>>(S, sdeg, cheb_b,
                                                            fc_w, fc_b, out);
}